// Round 1
// 143.013 us; speedup vs baseline: 1.0551x; 1.0551x over previous
//
#include <hip/hip_runtime.h>
#include <math.h>
#include <stdint.h>

#define BDIM 8
#define TDIM 2048
#define EDIM 1024
#define HDIM 64
#define NCHUNK 80    // CHUNK=8 tiles: sum over iq of ceil((iq+1)/8), iq in [0,32)

typedef short bf16x8 __attribute__((ext_vector_type(8)));   // 8 bf16 (4 VGPRs)
typedef float f32x4 __attribute__((ext_vector_type(4)));    // 4 fp32 acc
typedef uint32_t u32x2 __attribute__((ext_vector_type(2)));

__device__ __forceinline__ unsigned short f2bf(float f) {   // RNE fp32->bf16
    uint32_t u = __builtin_bit_cast(uint32_t, f);
    u += 0x7fffu + ((u >> 16) & 1u);
    return (unsigned short)(u >> 16);
}
__device__ __forceinline__ float bf2f(unsigned short s) {
    uint32_t u = ((uint32_t)s) << 16;
    return __builtin_bit_cast(float, u);
}
__device__ __forceinline__ uint32_t cvt_pk_bf16(float lo, float hi) {
    // dst[15:0]=bf16(lo), dst[31:16]=bf16(hi), RNE
    uint32_t r;
    asm("v_cvt_pk_bf16_f32 %0, %1, %2" : "=v"(r) : "v"(lo), "v"(hi));
    return r;
}

// ---------------------------------------------------------------------------
// prep_w: W[e][h] fp32 -> WT[h][e] bf16 (coalesced read, scattered write ~2us)
// ---------------------------------------------------------------------------
__global__ __launch_bounds__(256) void prep_w(
    const float* __restrict__ Wq, const float* __restrict__ Wk,
    const float* __restrict__ Wv,
    unsigned short* __restrict__ WqT, unsigned short* __restrict__ WkT,
    unsigned short* __restrict__ WvT)
{
    int id = blockIdx.x * 256 + threadIdx.x;   // 0..65535
    int e = id >> 6, h = id & 63;              // coalesced reads
    int oi = h * EDIM + e;
    WqT[oi] = f2bf(Wq[id]);
    WkT[oi] = f2bf(Wk[id]);
    WvT[oi] = f2bf(Wv[id]);
}

// ---------------------------------------------------------------------------
// proj (round-6 monolithic — kept, x-read BW-bound).  Grid 256 blocks, 256 thr.
// Q,K row-major [b*T][h]; V TRANSPOSED [b][d][T].
// ---------------------------------------------------------------------------
__global__ __launch_bounds__(256) void proj_kernel(
    const float* __restrict__ x,
    const unsigned short* __restrict__ WqT, const unsigned short* __restrict__ WkT,
    const unsigned short* __restrict__ WvT,
    const float* __restrict__ bq, const float* __restrict__ bk,
    const float* __restrict__ bv,
    unsigned short* __restrict__ Qb, unsigned short* __restrict__ Kb,
    unsigned short* __restrict__ VbT)
{
    __shared__ unsigned short Xs[2][64][72];   // row stride 144B (16B mult)
    __shared__ unsigned short Wqs[2][64][72];
    __shared__ unsigned short Wks[2][64][72];
    __shared__ unsigned short Wvs[2][64][72];

    const int t = threadIdx.x;
    const int lane = t & 63, w = t >> 6, quad = lane >> 4, ln = lane & 15;
    const int row0 = blockIdx.x * 64;
    const int sr = t >> 2;              // staging row 0..63
    const int sc = (t & 3) << 4;        // staging col 0,16,32,48

    f32x4 accq[4], acck[4], accv[4];
#pragma unroll
    for (int j = 0; j < 4; ++j) {
        accq[j] = (f32x4)(0.f); acck[j] = (f32x4)(0.f); accv[j] = (f32x4)(0.f);
    }

    const float* xp0  = &x[(size_t)(row0 + sr) * EDIM + sc];
    const size_t wrow = (size_t)sr * EDIM + sc;

    // ---- preload tile 0 into buf 0 ----
    {
        float4 x0 = *(const float4*)(xp0);
        float4 x1 = *(const float4*)(xp0 + 4);
        float4 x2 = *(const float4*)(xp0 + 8);
        float4 x3 = *(const float4*)(xp0 + 12);
        bf16x8 xb0, xb1;
        xb0[0]=(short)f2bf(x0.x); xb0[1]=(short)f2bf(x0.y); xb0[2]=(short)f2bf(x0.z); xb0[3]=(short)f2bf(x0.w);
        xb0[4]=(short)f2bf(x1.x); xb0[5]=(short)f2bf(x1.y); xb0[6]=(short)f2bf(x1.z); xb0[7]=(short)f2bf(x1.w);
        xb1[0]=(short)f2bf(x2.x); xb1[1]=(short)f2bf(x2.y); xb1[2]=(short)f2bf(x2.z); xb1[3]=(short)f2bf(x2.w);
        xb1[4]=(short)f2bf(x3.x); xb1[5]=(short)f2bf(x3.y); xb1[6]=(short)f2bf(x3.z); xb1[7]=(short)f2bf(x3.w);
        *(bf16x8*)&Xs[0][sr][sc]     = xb0;
        *(bf16x8*)&Xs[0][sr][sc + 8] = xb1;
        *(bf16x8*)&Wqs[0][sr][sc]     = *(const bf16x8*)&WqT[wrow];
        *(bf16x8*)&Wqs[0][sr][sc + 8] = *(const bf16x8*)&WqT[wrow + 8];
        *(bf16x8*)&Wks[0][sr][sc]     = *(const bf16x8*)&WkT[wrow];
        *(bf16x8*)&Wks[0][sr][sc + 8] = *(const bf16x8*)&WkT[wrow + 8];
        *(bf16x8*)&Wvs[0][sr][sc]     = *(const bf16x8*)&WvT[wrow];
        *(bf16x8*)&Wvs[0][sr][sc + 8] = *(const bf16x8*)&WvT[wrow + 8];
    }

    for (int kt = 0; kt < EDIM / 64; ++kt) {
        const int cur = kt & 1, nxt = cur ^ 1;

        // ---- issue next-tile global loads (in flight during MFMA) ----
        float4 x0, x1, x2, x3;
        bf16x8 wq0, wq1, wk0, wk1, wv0, wv1;
        if (kt < 15) {
            const float* xp = xp0 + (kt + 1) * 64;
            x0 = *(const float4*)(xp);
            x1 = *(const float4*)(xp + 4);
            x2 = *(const float4*)(xp + 8);
            x3 = *(const float4*)(xp + 12);
            const size_t wo = wrow + (kt + 1) * 64;
            wq0 = *(const bf16x8*)&WqT[wo];
            wq1 = *(const bf16x8*)&WqT[wo + 8];
            wk0 = *(const bf16x8*)&WkT[wo];
            wk1 = *(const bf16x8*)&WkT[wo + 8];
            wv0 = *(const bf16x8*)&WvT[wo];
            wv1 = *(const bf16x8*)&WvT[wo + 8];
        }

        __syncthreads();   // buf[cur] fully written (prev iter / preload)

        bf16x8 xa0 = *(const bf16x8*)&Xs[cur][16 * w + ln][8 * quad];
        bf16x8 xa1 = *(const bf16x8*)&Xs[cur][16 * w + ln][32 + 8 * quad];
#pragma unroll
        for (int j = 0; j < 4; ++j) {
            bf16x8 w0, w1;
            w0 = *(const bf16x8*)&Wqs[cur][16 * j + ln][8 * quad];
            w1 = *(const bf16x8*)&Wqs[cur][16 * j + ln][32 + 8 * quad];
            accq[j] = __builtin_amdgcn_mfma_f32_16x16x32_bf16(xa0, w0, accq[j], 0, 0, 0);
            accq[j] = __builtin_amdgcn_mfma_f32_16x16x32_bf16(xa1, w1, accq[j], 0, 0, 0);
            w0 = *(const bf16x8*)&Wks[cur][16 * j + ln][8 * quad];
            w1 = *(const bf16x8*)&Wks[cur][16 * j + ln][32 + 8 * quad];
            acck[j] = __builtin_amdgcn_mfma_f32_16x16x32_bf16(xa0, w0, acck[j], 0, 0, 0);
            acck[j] = __builtin_amdgcn_mfma_f32_16x16x32_bf16(xa1, w1, acck[j], 0, 0, 0);
            w0 = *(const bf16x8*)&Wvs[cur][16 * j + ln][8 * quad];
            w1 = *(const bf16x8*)&Wvs[cur][16 * j + ln][32 + 8 * quad];
            accv[j] = __builtin_amdgcn_mfma_f32_16x16x32_bf16(xa0, w0, accv[j], 0, 0, 0);
            accv[j] = __builtin_amdgcn_mfma_f32_16x16x32_bf16(xa1, w1, accv[j], 0, 0, 0);
        }

        // ---- convert + write next tile to alternate buffer ----
        if (kt < 15) {
            bf16x8 xb0, xb1;
            xb0[0]=(short)f2bf(x0.x); xb0[1]=(short)f2bf(x0.y); xb0[2]=(short)f2bf(x0.z); xb0[3]=(short)f2bf(x0.w);
            xb0[4]=(short)f2bf(x1.x); xb0[5]=(short)f2bf(x1.y); xb0[6]=(short)f2bf(x1.z); xb0[7]=(short)f2bf(x1.w);
            xb1[0]=(short)f2bf(x2.x); xb1[1]=(short)f2bf(x2.y); xb1[2]=(short)f2bf(x2.z); xb1[3]=(short)f2bf(x2.w);
            xb1[4]=(short)f2bf(x3.x); xb1[5]=(short)f2bf(x3.y); xb1[6]=(short)f2bf(x3.z); xb1[7]=(short)f2bf(x3.w);
            *(bf16x8*)&Xs[nxt][sr][sc]     = xb0;
            *(bf16x8*)&Xs[nxt][sr][sc + 8] = xb1;
            *(bf16x8*)&Wqs[nxt][sr][sc]     = wq0;
            *(bf16x8*)&Wqs[nxt][sr][sc + 8] = wq1;
            *(bf16x8*)&Wks[nxt][sr][sc]     = wk0;
            *(bf16x8*)&Wks[nxt][sr][sc + 8] = wk1;
            *(bf16x8*)&Wvs[nxt][sr][sc]     = wv0;
            *(bf16x8*)&Wvs[nxt][sr][sc + 8] = wv1;
        }
    }

    // epilogue: bias + bf16 store (C/D layout: row=4*quad+reg, col=ln+16j)
#pragma unroll
    for (int j = 0; j < 4; ++j) {
        int col = 16 * j + ln;
        float bqv = bq[col], bkv = bk[col], bvv = bv[col];
#pragma unroll
        for (int r = 0; r < 4; ++r) {
            size_t row = (size_t)(row0 + 16 * w + 4 * quad + r);
            Qb[row * HDIM + col] = f2bf(accq[j][r] + bqv);
            Kb[row * HDIM + col] = f2bf(acck[j][r] + bkv);
            int bb = (int)(row >> 11);            // row / TDIM
            int tr = (int)(row & 2047);           // row % TDIM
            VbT[((size_t)bb * HDIM + col) * TDIM + tr] = f2bf(accv[j][r] + bvv);
        }
    }
}

// ---------------------------------------------------------------------------
// Split-K flash partial, SWAPPED-QK^T variant: s = mfma(K, Q) puts a full
// q-row's 16 k-values in-lane -> softmax reduce is in-lane tree + 2 shfl_xor,
// P->bf16 is 8 cvt_pk + 4 ds_write_b64 (was 16 f2bf + 16 ds_write_b16).
// CHUNK=8 tiles/block (NCHUNK=80, grid 640 = ONE occupancy round at
// 3 blocks/CU), halves PO partial traffic.  Double-buffered K/V, one
// barrier per iteration, setprio(1) around MFMA clusters.
// ---------------------------------------------------------------------------
__global__ __launch_bounds__(256) void attn_partial(
    const unsigned short* __restrict__ Qb, const unsigned short* __restrict__ Kb,
    const unsigned short* __restrict__ VbT,
    unsigned short* __restrict__ PO, float* __restrict__ Pm, float* __restrict__ Pl)
{
    __shared__ unsigned short Ks[2][64][72];
    __shared__ unsigned short VsT[2][64][72];   // [d][k]
    __shared__ unsigned short Ps[64][72];       // [q][k] bf16, wave-private

    const int t = threadIdx.x;
    const int lane = t & 63, w = t >> 6, quad = lane >> 4, ln = lane & 15;
    const int f = blockIdx.x;
    const int b = blockIdx.y;

    // decode (iq, chunk): group g = iq>>3 has (g+1) chunks of 8 tiles each;
    // cumulative chunks through group g = 4*(g+1)*(g+2)
    int g = 0;
    while (f >= 4 * (g + 1) * (g + 2)) ++g;       // g in 0..3
    const int r_  = f - 4 * g * (g + 1);
    const int iq  = 8 * g + r_ / (g + 1);
    const int ch  = r_ % (g + 1);

    const int q0 = iq * 64;
    const size_t base = (size_t)b * TDIM * HDIM;
    const int sr = t >> 2;
    const int sc = (t & 3) << 4;

    const size_t qrow = base + (size_t)(q0 + 16 * w + ln) * HDIM;
    bf16x8 qa0 = *(const bf16x8*)&Qb[qrow + 8 * quad];
    bf16x8 qa1 = *(const bf16x8*)&Qb[qrow + 32 + 8 * quad];

    f32x4 od[4];
#pragma unroll
    for (int j = 0; j < 4; ++j) od[j] = (f32x4)(0.f);
    float m_run = -INFINITY, l_run = 0.f;   // state for q-row (16w+ln), replicated over quads

    const float scale = 0.125f;   // 1/sqrt(64)
    const int jt0 = 8 * ch;
    int j1 = jt0 + 7; if (j1 > iq) j1 = iq;

    // ---- preload tile jt0 into buf 0 ----
    {
        size_t ko = base + (size_t)(jt0 * 64 + sr) * HDIM + sc;
        *(bf16x8*)&Ks[0][sr][sc]     = *(const bf16x8*)&Kb[ko];
        *(bf16x8*)&Ks[0][sr][sc + 8] = *(const bf16x8*)&Kb[ko + 8];
        const unsigned short* vrow =
            &VbT[((size_t)b * HDIM + sr) * TDIM + jt0 * 64 + sc];
        *(bf16x8*)&VsT[0][sr][sc]     = *(const bf16x8*)vrow;
        *(bf16x8*)&VsT[0][sr][sc + 8] = *(const bf16x8*)(vrow + 8);
    }

    for (int jt = jt0; jt <= j1; ++jt) {
        const int cur = (jt - jt0) & 1, nxt = cur ^ 1;

        // ---- issue next-tile global loads (fly during compute) ----
        bf16x8 kn0, kn1, vn0, vn1;
        if (jt < j1) {
            size_t ko = base + (size_t)((jt + 1) * 64 + sr) * HDIM + sc;
            kn0 = *(const bf16x8*)&Kb[ko];
            kn1 = *(const bf16x8*)&Kb[ko + 8];
            const unsigned short* vrow =
                &VbT[((size_t)b * HDIM + sr) * TDIM + (jt + 1) * 64 + sc];
            vn0 = *(const bf16x8*)vrow;
            vn1 = *(const bf16x8*)(vrow + 8);
        }

        __syncthreads();   // buf[cur] ready; prev readers of buf[nxt] done

        // ---- S^T = K Q^T : lane(quad,ln) holds, per j, k = 16j+4*quad+r
        //      for the single q-row (16w+ln).  Same LDS/reg reads as before,
        //      only the mfma operand order is swapped. ----
        f32x4 s[4];
        __builtin_amdgcn_s_setprio(1);
#pragma unroll
        for (int j = 0; j < 4; ++j) {
            bf16x8 kb0 = *(const bf16x8*)&Ks[cur][16 * j + ln][8 * quad];
            bf16x8 kb1 = *(const bf16x8*)&Ks[cur][16 * j + ln][32 + 8 * quad];
            s[j] = (f32x4)(0.f);
            s[j] = __builtin_amdgcn_mfma_f32_16x16x32_bf16(kb0, qa0, s[j], 0, 0, 0);
            s[j] = __builtin_amdgcn_mfma_f32_16x16x32_bf16(kb1, qa1, s[j], 0, 0, 0);
        }
        __builtin_amdgcn_s_setprio(0);

        // ---- scale + causal mask (diagonal tile only) ----
        const int qg = q0 + 16 * w + ln;
        if (jt == iq) {
#pragma unroll
            for (int j = 0; j < 4; ++j) {
#pragma unroll
                for (int r = 0; r < 4; ++r) {
                    int kg = jt * 64 + 16 * j + 4 * quad + r;
                    s[j][r] = (kg <= qg) ? s[j][r] * scale : -INFINITY;
                }
            }
        } else {
#pragma unroll
            for (int j = 0; j < 4; ++j)
#pragma unroll
                for (int r = 0; r < 4; ++r) s[j][r] *= scale;
        }

        // ---- online softmax: in-lane tree over 16 + 2 quad shfl_xor ----
        float mx;
        {
            float a0 = fmaxf(fmaxf(s[0][0], s[0][1]), fmaxf(s[0][2], s[0][3]));
            float a1 = fmaxf(fmaxf(s[1][0], s[1][1]), fmaxf(s[1][2], s[1][3]));
            float a2 = fmaxf(fmaxf(s[2][0], s[2][1]), fmaxf(s[2][2], s[2][3]));
            float a3 = fmaxf(fmaxf(s[3][0], s[3][1]), fmaxf(s[3][2], s[3][3]));
            mx = fmaxf(fmaxf(a0, a1), fmaxf(a2, a3));
        }
        mx = fmaxf(mx, __shfl_xor(mx, 16));
        mx = fmaxf(mx, __shfl_xor(mx, 32));

        float mn = fmaxf(m_run, mx);
        float al = __expf(m_run - mn);     // first iter: exp(-inf - finite) = 0
        m_run = mn;

        float rs = 0.f;
#pragma unroll
        for (int j = 0; j < 4; ++j) {
            float p0 = __expf(s[j][0] - mn);
            float p1 = __expf(s[j][1] - mn);
            float p2 = __expf(s[j][2] - mn);
            float p3 = __expf(s[j][3] - mn);
            s[j][0] = p0; s[j][1] = p1; s[j][2] = p2; s[j][3] = p3;
            rs += (p0 + p1) + (p2 + p3);
        }
        rs += __shfl_xor(rs, 16);
        rs += __shfl_xor(rs, 32);
        l_run = l_run * al + rs;

        // ---- P -> LDS: 8 cvt_pk + 4 ds_write_b64 (k consecutive in-lane) ----
#pragma unroll
        for (int j = 0; j < 4; ++j) {
            u32x2 pk;
            pk.x = cvt_pk_bf16(s[j][0], s[j][1]);
            pk.y = cvt_pk_bf16(s[j][2], s[j][3]);
            *(u32x2*)&Ps[16 * w + ln][16 * j + 4 * quad] = pk;
        }

        // ---- rescale O (rows 16w+4*quad+r): fetch al of that row via shfl ----
#pragma unroll
        for (int r = 0; r < 4; ++r) {
            float alr = __shfl(al, 4 * quad + r);   // lane 4*quad+r holds row's al
#pragma unroll
            for (int j = 0; j < 4; ++j) od[j][r] *= alr;
        }

        // ---- O += P V ----
        bf16x8 pa0 = *(const bf16x8*)&Ps[16 * w + ln][8 * quad];
        bf16x8 pa1 = *(const bf16x8*)&Ps[16 * w + ln][32 + 8 * quad];
        __builtin_amdgcn_s_setprio(1);
#pragma unroll
        for (int j = 0; j < 4; ++j) {
            bf16x8 vb0 = *(const bf16x8*)&VsT[cur][16 * j + ln][8 * quad];
            bf16x8 vb1 = *(const bf16x8*)&VsT[cur][16 * j + ln][32 + 8 * quad];
            od[j] = __builtin_amdgcn_mfma_f32_16x16x32_bf16(pa0, vb0, od[j], 0, 0, 0);
            od[j] = __builtin_amdgcn_mfma_f32_16x16x32_bf16(pa1, vb1, od[j], 0, 0, 0);
        }
        __builtin_amdgcn_s_setprio(0);

        // ---- write next tile to alternate buffer ----
        if (jt < j1) {
            *(bf16x8*)&Ks[nxt][sr][sc]     = kn0;
            *(bf16x8*)&Ks[nxt][sr][sc + 8] = kn1;
            *(bf16x8*)&VsT[nxt][sr][sc]     = vn0;
            *(bf16x8*)&VsT[nxt][sr][sc + 8] = vn1;
        }
    }

    // ---- write partial (unnormalized O bf16, m/l fp32) ----
    const size_t p = (size_t)b * NCHUNK + f;
#pragma unroll
    for (int j = 0; j < 4; ++j)
#pragma unroll
        for (int r = 0; r < 4; ++r)
            PO[p * 4096 + (size_t)(16 * w + 4 * quad + r) * 64 + 16 * j + ln] =
                f2bf(od[j][r]);
    if (quad == 0) {   // lane < 16 owns q-row 16w+ln state directly now
        Pm[p * 64 + 16 * w + ln] = m_run;
        Pl[p * 64 + 16 * w + ln] = l_run;
    }
}

// ---------------------------------------------------------------------------
// Combine partials.  Grid (T/64, B), 256 thr.  Thread t: row=t>>2,
// cols (t&3)*16..+15.  nchunks = (iq>>3)+1 <= 4 now.
// ---------------------------------------------------------------------------
__global__ __launch_bounds__(256) void attn_combine(
    const unsigned short* __restrict__ PO, const float* __restrict__ Pm,
    const float* __restrict__ Pl, float* __restrict__ out)
{
    const int iq = blockIdx.x, b = blockIdx.y;
    const int g = iq >> 3;
    const int nch = g + 1;
    const int fbase = 4 * g * (g + 1) + (iq - 8 * g) * (g + 1);
    const int t = threadIdx.x;
    const int row = t >> 2;
    const int c0 = (t & 3) << 4;
    const size_t pbase = (size_t)b * NCHUNK + fbase;

    float M = -INFINITY;
    for (int c = 0; c < nch; ++c)
        M = fmaxf(M, Pm[(pbase + c) * 64 + row]);

    float a[16];
#pragma unroll
    for (int i = 0; i < 16; ++i) a[i] = 0.f;
    float L = 0.f;
    for (int c = 0; c < nch; ++c) {
        size_t p = pbase + c;
        float sc = __expf(Pm[p * 64 + row] - M);
        L += sc * Pl[p * 64 + row];
        const unsigned short* po = &PO[p * 4096 + (size_t)row * 64 + c0];
        bf16x8 v0 = *(const bf16x8*)(po);
        bf16x8 v1 = *(const bf16x8*)(po + 8);
#pragma unroll
        for (int i = 0; i < 8; ++i) {
            a[i]     += sc * bf2f((unsigned short)v0[i]);
            a[8 + i] += sc * bf2f((unsigned short)v1[i]);
        }
    }
    float li = 1.f / L;
    float4 o0, o1, o2, o3;
    o0.x=a[0]*li;  o0.y=a[1]*li;  o0.z=a[2]*li;  o0.w=a[3]*li;
    o1.x=a[4]*li;  o1.y=a[5]*li;  o1.z=a[6]*li;  o1.w=a[7]*li;
    o2.x=a[8]*li;  o2.y=a[9]*li;  o2.z=a[10]*li; o2.w=a[11]*li;
    o3.x=a[12]*li; o3.y=a[13]*li; o3.z=a[14]*li; o3.w=a[15]*li;
    float* op = &out[((size_t)b * TDIM + (size_t)iq * 64 + row) * HDIM + c0];
    *(float4*)(op)      = o0;
    *(float4*)(op + 4)  = o1;
    *(float4*)(op + 8)  = o2;
    *(float4*)(op + 12) = o3;
}

extern "C" void kernel_launch(void* const* d_in, const int* in_sizes, int n_in,
                              void* d_out, int out_size, void* d_ws, size_t ws_size,
                              hipStream_t stream) {
    const float* x  = (const float*)d_in[0];
    const float* Wq = (const float*)d_in[1];
    const float* bq = (const float*)d_in[2];
    const float* Wk = (const float*)d_in[3];
    const float* bk = (const float*)d_in[4];
    const float* Wv = (const float*)d_in[5];
    const float* bv = (const float*)d_in[6];
    float* out = (float*)d_out;

    const size_t n = (size_t)BDIM * TDIM * HDIM;     // 1,048,576
    unsigned short* Qb  = (unsigned short*)d_ws;
    unsigned short* Kb  = Qb + n;
    unsigned short* VbT = Kb + n;
    unsigned short* WqT = VbT + n;
    unsigned short* WkT = WqT + (size_t)EDIM * HDIM;
    unsigned short* WvT = WkT + (size_t)EDIM * HDIM;
    unsigned short* PO  = WvT + (size_t)EDIM * HDIM;           // 640*4096 bf16 per batch-set
    float* Pm = (float*)(PO + (size_t)BDIM * NCHUNK * 4096);   // 640*64
    float* Pl = Pm + (size_t)BDIM * NCHUNK * 64;

    prep_w<<<dim3(EDIM * HDIM / 256), 256, 0, stream>>>(Wq, Wk, Wv, WqT, WkT, WvT);
    proj_kernel<<<dim3(BDIM * TDIM / 64), 256, 0, stream>>>(
        x, WqT, WkT, WvT, bq, bk, bv, Qb, Kb, VbT);
    attn_partial<<<dim3(NCHUNK, BDIM), 256, 0, stream>>>(Qb, Kb, VbT, PO, Pm, Pl);
    attn_combine<<<dim3(TDIM / 64, BDIM), 256, 0, stream>>>(PO, Pm, Pl, out);
}